// Round 1
// baseline (181.249 us; speedup 1.0000x reference)
//
#include <hip/hip_runtime.h>

// AnchorTarget (pysot) for b=128, G=64, SCORE=25, A=5, STRIDE=8.
// Outputs concatenated as float32: cls(128,5,25,25) | bt(128,4,5,25,25) |
// bw(128,5,25,25) | max_ov(128,3125). Total 2,800,000 floats.

namespace {
constexpr int B_    = 128;
constexpr int N_    = 3125;   // 25*25*5
constexpr int G_    = 64;
constexpr int A_    = 5;
constexpr int S_    = 25;
constexpr int NT    = 1024;
constexpr int CHUNK = 4;      // ceil(3125/1024)
constexpr int POSN  = 16;
constexpr int TOTN  = 64;

constexpr int CLS_OFF = 0;
constexpr int BT_OFF  = B_ * A_ * S_ * S_;            // 400000
constexpr int BW_OFF  = BT_OFF + B_ * 4 * A_ * S_ * S_; // 2000000
constexpr int MO_OFF  = BW_OFF + B_ * A_ * S_ * S_;   // 2400000
}

__device__ __forceinline__ float iou_f(float a0, float a1, float a2, float a3,
                                       float aarea, float g0, float g1,
                                       float g2, float g3, float garea) {
  // exactly mirrors numpy op order: ((min-max)+1), clip, mul, (a+g)-inter, div
  float ix = (fminf(a2, g2) - fmaxf(a0, g0)) + 1.0f;
  float iy = (fminf(a3, g3) - fmaxf(a1, g1)) + 1.0f;
  ix = fmaxf(ix, 0.0f);
  iy = fmaxf(iy, 0.0f);
  float inter = ix * iy;
  return inter / ((aarea + garea) - inter);
}

__global__ __launch_bounds__(NT) void at_main_kernel(
    const float* __restrict__ gt,      // (128,64,4)
    const float* __restrict__ anchors, // (3125,4)
    float* __restrict__ out,           // 2.8M floats
    int* __restrict__ pos_ws) {
  const int bb = blockIdx.x;
  const int t  = threadIdx.x;

  __shared__ float    s_gt[G_ * 4];
  __shared__ float    s_garea[G_];
  __shared__ unsigned s_gtmax_bits[G_];
  __shared__ float    s_gtmax[G_];     // adjusted (0 -> 1e-5)
  __shared__ int      s_cls[N_];
  __shared__ int      s_sp[NT];
  __shared__ int      s_sn[NT];

  if (t < G_ * 4) s_gt[t] = gt[bb * (G_ * 4) + t];
  if (t < G_) s_gtmax_bits[t] = 0u;
  __syncthreads();
  if (t < G_) {
    float g0 = s_gt[t * 4 + 0], g1 = s_gt[t * 4 + 1];
    float g2 = s_gt[t * 4 + 2], g3 = s_gt[t * 4 + 3];
    s_garea[t] = ((g2 - g0) + 1.0f) * ((g3 - g1) + 1.0f);
  }
  __syncthreads();

  // ---------------- phase 1: gt_max[g] = max_n iou(n,g) ----------------
  {
    const int g   = t & 63;
    const int seg = t >> 6;           // 0..15
    const float g0 = s_gt[g * 4 + 0], g1 = s_gt[g * 4 + 1];
    const float g2 = s_gt[g * 4 + 2], g3 = s_gt[g * 4 + 3];
    const float garea = s_garea[g];
    float gmax = 0.0f;                // iou >= 0 always
    for (int n = seg; n < N_; n += NT / 64) {
      const float a0 = anchors[n * 4 + 0], a1 = anchors[n * 4 + 1];
      const float a2 = anchors[n * 4 + 2], a3 = anchors[n * 4 + 3];
      const float aarea = ((a2 - a0) + 1.0f) * ((a3 - a1) + 1.0f);
      const float v = iou_f(a0, a1, a2, a3, aarea, g0, g1, g2, g3, garea);
      gmax = fmaxf(gmax, v);
    }
    // non-negative floats: bit pattern order == float order
    atomicMax(&s_gtmax_bits[g], __float_as_uint(gmax));
  }
  __syncthreads();
  if (t < G_) {
    const float v = __uint_as_float(s_gtmax_bits[t]);
    s_gtmax[t] = (v == 0.0f) ? 1e-5f : v;
  }
  __syncthreads();

  // ---------------- phase 2: per-anchor max/arg/keep/cls0, bt, max_ov ----
  const int n0 = t * CHUNK;
  const int n1 = (n0 + CHUNK < N_) ? (n0 + CHUNK) : N_;

  float* __restrict__ out_bt = out + BT_OFF;
  float* __restrict__ out_mo = out + MO_OFF;

  int myp = 0, myn = 0;
  for (int n = n0; n < n1; ++n) {
    const float a0 = anchors[n * 4 + 0], a1 = anchors[n * 4 + 1];
    const float a2 = anchors[n * 4 + 2], a3 = anchors[n * 4 + 3];
    const float aw = (a2 - a0) + 1.0f;
    const float ah = (a3 - a1) + 1.0f;
    const float aarea = aw * ah;

    float best = -1.0f;
    int   barg = 0;
    int   keep = 0;
    for (int g = 0; g < G_; ++g) {
      const float g0 = s_gt[g * 4 + 0], g1 = s_gt[g * 4 + 1];
      const float g2 = s_gt[g * 4 + 2], g3 = s_gt[g * 4 + 3];
      const float v =
          iou_f(a0, a1, a2, a3, aarea, g0, g1, g2, g3, s_garea[g]);
      if (v > best) { best = v; barg = g; }   // first-occurrence argmax
      if (v == s_gtmax[g]) keep = 1;          // bit-exact recompute
    }

    int c = -1;
    if (best >= 0.6f) c = 1;
    if (best <= 0.3f) c = 0;
    if (keep) c = 1;
    s_cls[n] = c;
    if (c == 1) ++myp;
    else if (c == 0) ++myn;

    // bbox transform vs matched gt
    const float m0 = s_gt[barg * 4 + 0], m1 = s_gt[barg * 4 + 1];
    const float m2 = s_gt[barg * 4 + 2], m3 = s_gt[barg * 4 + 3];
    const float gw  = (m2 - m0) + 1.0f;
    const float gh  = (m3 - m1) + 1.0f;
    const float acx = a0 + 0.5f * aw;
    const float acy = a1 + 0.5f * ah;
    const float gcx = m0 + 0.5f * gw;
    const float gcy = m1 + 0.5f * gh;
    const float dx = (gcx - acx) / aw;
    const float dy = (gcy - acy) / ah;
    const float dw = __logf(gw / aw) == __logf(gw / aw) ? logf(gw / aw) : logf(gw / aw);
    const float dh = logf(gh / ah);

    // layout: n = (y*25 + x)*5 + a
    const int a   = n % A_;
    const int rem = n / A_;
    const int x   = rem % S_;
    const int y   = rem / S_;
    const int spat = y * S_ + x;                    // 0..624
    const int btb  = ((bb * 4 + 0) * A_ + a) * (S_ * S_) + spat;
    out_bt[btb + 0 * A_ * S_ * S_] = dx;
    out_bt[btb + 1 * A_ * S_ * S_] = dy;
    out_bt[btb + 2 * A_ * S_ * S_] = logf(gw / aw);
    out_bt[btb + 3 * A_ * S_ * S_] = dh;
    (void)dw;
    out_mo[bb * N_ + n] = best;
  }
  __syncthreads();

  // ---------------- phase 3: prefix scan of pos/neg counts --------------
  s_sp[t] = myp;
  s_sn[t] = myn;
  __syncthreads();
  for (int off = 1; off < NT; off <<= 1) {
    int vp = 0, vn = 0;
    if (t >= off) { vp = s_sp[t - off]; vn = s_sn[t - off]; }
    __syncthreads();
    s_sp[t] += vp;
    s_sn[t] += vn;
    __syncthreads();
  }

  if (bb == B_ - 1 && t == 0) {
    const int tot = s_sp[NT - 1];
    pos_ws[0] = (tot < POSN) ? tot : POSN;  // first-16 cap => min(tot,16)
  }

  int runp = s_sp[t] - myp;  // exclusive prefix
  int runn = s_sn[t] - myn;
  float* __restrict__ out_cls = out + CLS_OFF;
  for (int n = n0; n < n1; ++n) {
    int c = s_cls[n];
    if (c == 1) {
      ++runp;
      if (runp > POSN) c = -1;
    } else if (c == 0) {
      ++runn;
      if (runn > TOTN) c = -1;
    }
    const int a   = n % A_;
    const int rem = n / A_;
    const int x   = rem % S_;
    const int y   = rem / S_;
    out_cls[((bb * A_ + a) * S_ + y) * S_ + x] = (float)c;
  }
}

__global__ __launch_bounds__(256) void at_bw_kernel(
    const float* __restrict__ out_cls, float* __restrict__ out_bw,
    const int* __restrict__ pos_ws) {
  const int i = blockIdx.x * blockDim.x + threadIdx.x;
  if (i >= B_ * A_ * S_ * S_) return;
  const float inv = 1.0f / (float)pos_ws[0];  // replicate ref (inf if 0)
  const float c = out_cls[i];
  out_bw[i] = (c == 1.0f) ? inv : 0.0f;
}

extern "C" void kernel_launch(void* const* d_in, const int* in_sizes, int n_in,
                              void* d_out, int out_size, void* d_ws,
                              size_t ws_size, hipStream_t stream) {
  const float* gt      = (const float*)d_in[0];  // (128,64,4)
  const float* anchors = (const float*)d_in[1];  // (3125,4)
  float* out = (float*)d_out;
  int* pos_ws = (int*)d_ws;

  at_main_kernel<<<B_, NT, 0, stream>>>(gt, anchors, out, pos_ws);

  const int nbw = B_ * A_ * S_ * S_;  // 400000
  at_bw_kernel<<<(nbw + 255) / 256, 256, 0, stream>>>(out + CLS_OFF,
                                                      out + BW_OFF, pos_ws);
}

// Round 2
// 143.918 us; speedup vs baseline: 1.2594x; 1.2594x over previous
//
#include <hip/hip_runtime.h>

// AnchorTarget (pysot) for b=128, G=64, SCORE=25, A=5, STRIDE=8.
// Outputs concatenated as float32: cls(128,5,25,25) | bt(128,4,5,25,25) |
// bw(128,5,25,25) | max_ov(128,3125). Total 2,800,000 floats.
//
// Round 2: full-chip parallel restructure. 4 kernels:
//   memset ws -> k1_gtmax (896 blk) -> k2_anchor (1664 blk) -> k3_caps (128 blk)
//   -> at_bw (1563 blk).
// Cross-kernel float-equality (keep test) protected by fp contract(off) in the
// shared IoU helper used by both k1 and k2.

namespace {
constexpr int B_   = 128;
constexpr int N_   = 3125;   // 25*25*5
constexpr int G_   = 64;
constexpr int A_   = 5;
constexpr int S_   = 25;
constexpr int POSN = 16;
constexpr int TOTN = 64;

constexpr int CLS_OFF = 0;
constexpr int BT_OFF  = B_ * A_ * S_ * S_;              // 400000
constexpr int BW_OFF  = BT_OFF + B_ * 4 * A_ * S_ * S_; // 2000000
constexpr int MO_OFF  = BW_OFF + B_ * A_ * S_ * S_;     // 2400000
}

__device__ __forceinline__ float area_f(float x0, float y0, float x1, float y1) {
#pragma clang fp contract(off)
  return ((x1 - x0) + 1.0f) * ((y1 - y0) + 1.0f);
}

__device__ __forceinline__ float iou_f(float a0, float a1, float a2, float a3,
                                       float aarea, float g0, float g1,
                                       float g2, float g3, float garea) {
#pragma clang fp contract(off)
  // exactly mirrors numpy op order: ((min-max)+1), clip, mul, (a+g)-inter, div
  float ix = (fminf(a2, g2) - fmaxf(a0, g0)) + 1.0f;
  float iy = (fminf(a3, g3) - fmaxf(a1, g1)) + 1.0f;
  ix = fmaxf(ix, 0.0f);
  iy = fmaxf(iy, 0.0f);
  float inter = ix * iy;
  return inter / ((aarea + garea) - inter);
}

// ---- K1: gt_max[b][g] = max_n iou(n,g), as uint bits (iou >= 0) -----------
// block = 256 thr: g = t&63 (lane-varying), w = t>>6 (wave id) -> anchor index
// is wave-uniform => scalar loads for anchors. Grid (7, 128): 512 anchors/blk.
__global__ __launch_bounds__(256) void k1_gtmax(
    const float* __restrict__ gt,       // (128,64,4)
    const float* __restrict__ anchors,  // (3125,4)
    unsigned* __restrict__ gtmax) {     // (128,64) bits, pre-zeroed
#pragma clang fp contract(off)
  const int b = blockIdx.y;
  const int t = threadIdx.x;
  const int g = t & 63;
  const int w = t >> 6;  // 0..3

  __shared__ unsigned s_max[G_];
  if (t < G_) s_max[t] = 0u;

  const float4 gg = ((const float4*)gt)[b * G_ + g];  // coalesced per-lane
  const float garea = area_f(gg.x, gg.y, gg.z, gg.w);
  __syncthreads();

  float gmax = 0.0f;
  const int nbase = blockIdx.x * 512 + w;
#pragma unroll 4
  for (int i = 0; i < 128; ++i) {
    const int n = nbase + i * 4;  // wave-uniform
    if (n < N_) {
      const float4 aa = ((const float4*)anchors)[n];  // uniform -> s_load
      const float aarea = area_f(aa.x, aa.y, aa.z, aa.w);
      const float v =
          iou_f(aa.x, aa.y, aa.z, aa.w, aarea, gg.x, gg.y, gg.z, gg.w, garea);
      gmax = fmaxf(gmax, v);
    }
  }
  atomicMax(&s_max[g], __float_as_uint(gmax));
  __syncthreads();
  if (t < G_) atomicMax(&gtmax[b * G_ + t], s_max[t]);
}

// ---- K2: per-anchor row: best/arg/keep -> cls0, bt, max_ov ----------------
// Grid (13, 128), 256 thr, 1 anchor per thread.
__global__ __launch_bounds__(256) void k2_anchor(
    const float* __restrict__ gt, const float* __restrict__ anchors,
    const unsigned* __restrict__ gtmax, float* __restrict__ out) {
#pragma clang fp contract(off)
  const int b = blockIdx.y;
  const int t = threadIdx.x;
  const int n = blockIdx.x * 256 + t;

  __shared__ float s_gt[G_ * 4];
  __shared__ float s_garea[G_];
  __shared__ float s_gtmax[G_];

  s_gt[t] = gt[b * G_ * 4 + t];  // 256 floats == whole gt row
  __syncthreads();
  if (t < G_) {
    s_garea[t] =
        area_f(s_gt[t * 4 + 0], s_gt[t * 4 + 1], s_gt[t * 4 + 2], s_gt[t * 4 + 3]);
    const float v = __uint_as_float(gtmax[b * G_ + t]);
    s_gtmax[t] = (v == 0.0f) ? 1e-5f : v;
  }
  __syncthreads();

  if (n >= N_) return;

  const float4 aa = ((const float4*)anchors)[n];
  const float aw = (aa.z - aa.x) + 1.0f;
  const float ah = (aa.w - aa.y) + 1.0f;
  const float aarea = aw * ah;  // same ops/order as area_f

  float best = -1.0f;
  int barg = 0;
  int keep = 0;
#pragma unroll 8
  for (int g = 0; g < G_; ++g) {
    const float4 gg = *(const float4*)&s_gt[g * 4];  // broadcast ds_read_b128
    const float v =
        iou_f(aa.x, aa.y, aa.z, aa.w, aarea, gg.x, gg.y, gg.z, gg.w, s_garea[g]);
    if (v > best) { best = v; barg = g; }  // first-occurrence argmax
    keep |= (v == s_gtmax[g]);             // bit-exact vs K1
  }

  int c = -1;
  if (best >= 0.6f) c = 1;
  if (best <= 0.3f) c = 0;
  if (keep) c = 1;

  // bbox transform vs matched gt
  const float m0 = s_gt[barg * 4 + 0], m1 = s_gt[barg * 4 + 1];
  const float m2 = s_gt[barg * 4 + 2], m3 = s_gt[barg * 4 + 3];
  const float gw = (m2 - m0) + 1.0f;
  const float gh = (m3 - m1) + 1.0f;
  const float acx = aa.x + 0.5f * aw;
  const float acy = aa.y + 0.5f * ah;
  const float gcx = m0 + 0.5f * gw;
  const float gcy = m1 + 0.5f * gh;
  const float dx = (gcx - acx) / aw;
  const float dy = (gcy - acy) / ah;
  const float dw = logf(gw / aw);
  const float dh = logf(gh / ah);

  // layout: n = (y*25 + x)*5 + a
  const int a = n % A_;
  const int rem = n / A_;
  const int x = rem % S_;
  const int y = rem / S_;
  const int spat = y * S_ + x;

  float* __restrict__ out_bt = out + BT_OFF;
  const int btb = ((b * 4 + 0) * A_ + a) * (S_ * S_) + spat;
  out_bt[btb + 0 * A_ * S_ * S_] = dx;
  out_bt[btb + 1 * A_ * S_ * S_] = dy;
  out_bt[btb + 2 * A_ * S_ * S_] = dw;
  out_bt[btb + 3 * A_ * S_ * S_] = dh;

  out[CLS_OFF + ((b * A_ + a) * S_ + y) * S_ + x] = (float)c;
  out[MO_OFF + b * N_ + n] = best;
}

// ---- K3: per-batch prefix caps on cls (first 16 pos / first 64 neg) -------
__global__ __launch_bounds__(256) void k3_caps(float* __restrict__ out,
                                               int* __restrict__ pos_ws) {
  const int b = blockIdx.x;
  const int t = threadIdx.x;
  __shared__ int s_p[256];
  __shared__ int s_n[256];

  float* __restrict__ out_cls = out + CLS_OFF;
  const int n0 = t * 13;

  float cvals[13];
  int myp = 0, myn = 0;
#pragma unroll
  for (int k = 0; k < 13; ++k) {
    const int n = n0 + k;
    float c = -1.0f;
    if (n < N_) {
      const int a = n % A_;
      const int rem = n / A_;
      const int x = rem % S_;
      const int y = rem / S_;
      c = out_cls[((b * A_ + a) * S_ + y) * S_ + x];
      if (c == 1.0f) ++myp;
      else if (c == 0.0f) ++myn;
    }
    cvals[k] = c;
  }
  s_p[t] = myp;
  s_n[t] = myn;
  __syncthreads();
  for (int off = 1; off < 256; off <<= 1) {
    int vp = 0, vn = 0;
    if (t >= off) { vp = s_p[t - off]; vn = s_n[t - off]; }
    __syncthreads();
    s_p[t] += vp;
    s_n[t] += vn;
    __syncthreads();
  }

  int runp = s_p[t] - myp;  // exclusive prefix
  int runn = s_n[t] - myn;
#pragma unroll
  for (int k = 0; k < 13; ++k) {
    const int n = n0 + k;
    if (n >= N_) break;
    float c = cvals[k];
    if (c == 1.0f) {
      if (++runp > POSN) c = -1.0f;
    } else if (c == 0.0f) {
      if (++runn > TOTN) c = -1.0f;
    }
    const int a = n % A_;
    const int rem = n / A_;
    const int x = rem % S_;
    const int y = rem / S_;
    out_cls[((b * A_ + a) * S_ + y) * S_ + x] = c;
  }

  if (b == B_ - 1 && t == 255) {
    const int tot = s_p[255];
    pos_ws[0] = (tot < POSN) ? tot : POSN;  // count of cls==1 after capping
  }
}

// ---- K4: bw = (cls==1) ? 1/pos_num : 0 ------------------------------------
__global__ __launch_bounds__(256) void at_bw_kernel(
    const float* __restrict__ out_cls, float* __restrict__ out_bw,
    const int* __restrict__ pos_ws) {
  const int i = blockIdx.x * blockDim.x + threadIdx.x;
  if (i >= B_ * A_ * S_ * S_) return;
  const float inv = 1.0f / (float)pos_ws[0];  // inf if 0, matching ref
  const float c = out_cls[i];
  out_bw[i] = (c == 1.0f) ? inv : 0.0f;
}

extern "C" void kernel_launch(void* const* d_in, const int* in_sizes, int n_in,
                              void* d_out, int out_size, void* d_ws,
                              size_t ws_size, hipStream_t stream) {
  const float* gt = (const float*)d_in[0];       // (128,64,4)
  const float* anchors = (const float*)d_in[1];  // (3125,4)
  float* out = (float*)d_out;
  int* pos_ws = (int*)d_ws;
  unsigned* gtmax = (unsigned*)d_ws + 64;  // 128*64 uints = 32 KB

  // zero pos_num + gt_max table (ws is poisoned 0xAA before every call)
  hipMemsetAsync(d_ws, 0, 64 * sizeof(int) + B_ * G_ * sizeof(unsigned),
                 stream);

  k1_gtmax<<<dim3(7, B_), 256, 0, stream>>>(gt, anchors, gtmax);
  k2_anchor<<<dim3(13, B_), 256, 0, stream>>>(gt, anchors, gtmax, out);
  k3_caps<<<B_, 256, 0, stream>>>(out, pos_ws);

  const int nbw = B_ * A_ * S_ * S_;  // 400000
  at_bw_kernel<<<(nbw + 255) / 256, 256, 0, stream>>>(out + CLS_OFF,
                                                      out + BW_OFF, pos_ws);
}

// Round 3
// 123.369 us; speedup vs baseline: 1.4692x; 1.1666x over previous
//
#include <hip/hip_runtime.h>

// AnchorTarget (pysot) for b=128, G=64, SCORE=25, A=5, STRIDE=8.
// Outputs concatenated as float32: cls(128,5,25,25) | bt(128,4,5,25,25) |
// bw(128,5,25,25) | max_ov(128,3125). Total 2,800,000 floats.
//
// Round 3: k1 rewritten as wave-per-(b,g): per-lane coalesced anchor loads,
// shfl-xor max reduce, single writer per slot (no atomics, no ws memset).
// Cross-kernel float-equality (keep test) protected by fp contract(off) in the
// shared IoU helper used by both k1 and k2.

namespace {
constexpr int B_   = 128;
constexpr int N_   = 3125;   // 25*25*5
constexpr int G_   = 64;
constexpr int A_   = 5;
constexpr int S_   = 25;
constexpr int POSN = 16;
constexpr int TOTN = 64;

constexpr int CLS_OFF = 0;
constexpr int BT_OFF  = B_ * A_ * S_ * S_;              // 400000
constexpr int BW_OFF  = BT_OFF + B_ * 4 * A_ * S_ * S_; // 2000000
constexpr int MO_OFF  = BW_OFF + B_ * A_ * S_ * S_;     // 2400000
}

__device__ __forceinline__ float area_f(float x0, float y0, float x1, float y1) {
#pragma clang fp contract(off)
  return ((x1 - x0) + 1.0f) * ((y1 - y0) + 1.0f);
}

__device__ __forceinline__ float iou_f(float a0, float a1, float a2, float a3,
                                       float aarea, float g0, float g1,
                                       float g2, float g3, float garea) {
#pragma clang fp contract(off)
  // exactly mirrors numpy op order: ((min-max)+1), clip, mul, (a+g)-inter, div
  float ix = (fminf(a2, g2) - fmaxf(a0, g0)) + 1.0f;
  float iy = (fminf(a3, g3) - fmaxf(a1, g1)) + 1.0f;
  ix = fmaxf(ix, 0.0f);
  iy = fmaxf(iy, 0.0f);
  float inter = ix * iy;
  return inter / ((aarea + garea) - inter);
}

// ---- K1: gt_max[b][g] = max_n iou(n,g) ------------------------------------
// One wave per (b,g). Lanes sweep anchors coalesced (float4/lane), running
// per-lane max, then 6-step shfl-xor reduce; lane 0 stores the final float.
// Grid: 8192 waves -> 2048 blocks of 256.
__global__ __launch_bounds__(256) void k1_gtmax(
    const float* __restrict__ gt,       // (128,64,4)
    const float* __restrict__ anchors,  // (3125,4)
    float* __restrict__ gtmax) {        // (128,64) floats
#pragma clang fp contract(off)
  const int t    = threadIdx.x;
  const int lane = t & 63;
  const int W    = blockIdx.x * 4 + (t >> 6);  // global wave id
  const int b    = W >> 6;
  const int g    = W & 63;

  const float4 gg = ((const float4*)gt)[b * G_ + g];  // wave-uniform
  const float garea = area_f(gg.x, gg.y, gg.z, gg.w);

  float gmax = 0.0f;  // iou >= 0 always
  // 3125 = 48*64 + 53 ; full iterations then a guarded tail
#pragma unroll 4
  for (int i = 0; i < 48; ++i) {
    const int n = i * 64 + lane;  // per-lane coalesced
    const float4 aa = ((const float4*)anchors)[n];
    const float aarea = area_f(aa.x, aa.y, aa.z, aa.w);
    gmax = fmaxf(gmax, iou_f(aa.x, aa.y, aa.z, aa.w, aarea,
                             gg.x, gg.y, gg.z, gg.w, garea));
  }
  {
    const int n = 48 * 64 + lane;
    if (n < N_) {
      const float4 aa = ((const float4*)anchors)[n];
      const float aarea = area_f(aa.x, aa.y, aa.z, aa.w);
      gmax = fmaxf(gmax, iou_f(aa.x, aa.y, aa.z, aa.w, aarea,
                               gg.x, gg.y, gg.z, gg.w, garea));
    }
  }
  // wave max-reduce (fmax is associative/commutative; values are plain floats)
#pragma unroll
  for (int off = 32; off > 0; off >>= 1)
    gmax = fmaxf(gmax, __shfl_xor(gmax, off, 64));

  if (lane == 0) gtmax[b * G_ + g] = gmax;
}

// ---- K2: per-anchor row: best/arg/keep -> cls0, bt, max_ov ----------------
// Grid (13, 128), 256 thr, 1 anchor per thread.
__global__ __launch_bounds__(256) void k2_anchor(
    const float* __restrict__ gt, const float* __restrict__ anchors,
    const float* __restrict__ gtmax, float* __restrict__ out) {
#pragma clang fp contract(off)
  const int b = blockIdx.y;
  const int t = threadIdx.x;
  const int n = blockIdx.x * 256 + t;

  __shared__ float s_gt[G_ * 4];
  __shared__ float s_garea[G_];
  __shared__ float s_gtmax[G_];

  s_gt[t] = gt[b * G_ * 4 + t];  // 256 floats == whole gt row
  __syncthreads();
  if (t < G_) {
    s_garea[t] =
        area_f(s_gt[t * 4 + 0], s_gt[t * 4 + 1], s_gt[t * 4 + 2], s_gt[t * 4 + 3]);
    const float v = gtmax[b * G_ + t];
    s_gtmax[t] = (v == 0.0f) ? 1e-5f : v;
  }
  __syncthreads();

  if (n >= N_) return;

  const float4 aa = ((const float4*)anchors)[n];
  const float aw = (aa.z - aa.x) + 1.0f;
  const float ah = (aa.w - aa.y) + 1.0f;
  const float aarea = aw * ah;  // same ops/order as area_f

  float best = -1.0f;
  int barg = 0;
  int keep = 0;
#pragma unroll 8
  for (int g = 0; g < G_; ++g) {
    const float4 gg = *(const float4*)&s_gt[g * 4];  // broadcast ds_read_b128
    const float v =
        iou_f(aa.x, aa.y, aa.z, aa.w, aarea, gg.x, gg.y, gg.z, gg.w, s_garea[g]);
    if (v > best) { best = v; barg = g; }  // first-occurrence argmax
    keep |= (v == s_gtmax[g]);             // bit-exact vs K1
  }

  int c = -1;
  if (best >= 0.6f) c = 1;
  if (best <= 0.3f) c = 0;
  if (keep) c = 1;

  // bbox transform vs matched gt
  const float m0 = s_gt[barg * 4 + 0], m1 = s_gt[barg * 4 + 1];
  const float m2 = s_gt[barg * 4 + 2], m3 = s_gt[barg * 4 + 3];
  const float gw = (m2 - m0) + 1.0f;
  const float gh = (m3 - m1) + 1.0f;
  const float acx = aa.x + 0.5f * aw;
  const float acy = aa.y + 0.5f * ah;
  const float gcx = m0 + 0.5f * gw;
  const float gcy = m1 + 0.5f * gh;
  const float dx = (gcx - acx) / aw;
  const float dy = (gcy - acy) / ah;
  const float dw = logf(gw / aw);
  const float dh = logf(gh / ah);

  // layout: n = (y*25 + x)*5 + a
  const int a = n % A_;
  const int rem = n / A_;
  const int x = rem % S_;
  const int y = rem / S_;
  const int spat = y * S_ + x;

  float* __restrict__ out_bt = out + BT_OFF;
  const int btb = ((b * 4 + 0) * A_ + a) * (S_ * S_) + spat;
  out_bt[btb + 0 * A_ * S_ * S_] = dx;
  out_bt[btb + 1 * A_ * S_ * S_] = dy;
  out_bt[btb + 2 * A_ * S_ * S_] = dw;
  out_bt[btb + 3 * A_ * S_ * S_] = dh;

  out[CLS_OFF + ((b * A_ + a) * S_ + y) * S_ + x] = (float)c;
  out[MO_OFF + b * N_ + n] = best;
}

// ---- K3: per-batch prefix caps on cls (first 16 pos / first 64 neg) -------
__global__ __launch_bounds__(256) void k3_caps(float* __restrict__ out,
                                               int* __restrict__ pos_ws) {
  const int b = blockIdx.x;
  const int t = threadIdx.x;
  __shared__ int s_p[256];
  __shared__ int s_n[256];

  float* __restrict__ out_cls = out + CLS_OFF;
  const int n0 = t * 13;

  float cvals[13];
  int myp = 0, myn = 0;
#pragma unroll
  for (int k = 0; k < 13; ++k) {
    const int n = n0 + k;
    float c = -1.0f;
    if (n < N_) {
      const int a = n % A_;
      const int rem = n / A_;
      const int x = rem % S_;
      const int y = rem / S_;
      c = out_cls[((b * A_ + a) * S_ + y) * S_ + x];
      if (c == 1.0f) ++myp;
      else if (c == 0.0f) ++myn;
    }
    cvals[k] = c;
  }
  s_p[t] = myp;
  s_n[t] = myn;
  __syncthreads();
  for (int off = 1; off < 256; off <<= 1) {
    int vp = 0, vn = 0;
    if (t >= off) { vp = s_p[t - off]; vn = s_n[t - off]; }
    __syncthreads();
    s_p[t] += vp;
    s_n[t] += vn;
    __syncthreads();
  }

  int runp = s_p[t] - myp;  // exclusive prefix
  int runn = s_n[t] - myn;
#pragma unroll
  for (int k = 0; k < 13; ++k) {
    const int n = n0 + k;
    if (n >= N_) break;
    float c = cvals[k];
    if (c == 1.0f) {
      if (++runp > POSN) c = -1.0f;
    } else if (c == 0.0f) {
      if (++runn > TOTN) c = -1.0f;
    }
    const int a = n % A_;
    const int rem = n / A_;
    const int x = rem % S_;
    const int y = rem / S_;
    out_cls[((b * A_ + a) * S_ + y) * S_ + x] = c;
  }

  if (b == B_ - 1 && t == 255) {
    const int tot = s_p[255];
    pos_ws[0] = (tot < POSN) ? tot : POSN;  // count of cls==1 after capping
  }
}

// ---- K4: bw = (cls==1) ? 1/pos_num : 0 ------------------------------------
__global__ __launch_bounds__(256) void at_bw_kernel(
    const float* __restrict__ out_cls, float* __restrict__ out_bw,
    const int* __restrict__ pos_ws) {
  const int i = blockIdx.x * blockDim.x + threadIdx.x;
  if (i >= B_ * A_ * S_ * S_) return;
  const float inv = 1.0f / (float)pos_ws[0];  // inf if 0, matching ref
  const float c = out_cls[i];
  out_bw[i] = (c == 1.0f) ? inv : 0.0f;
}

extern "C" void kernel_launch(void* const* d_in, const int* in_sizes, int n_in,
                              void* d_out, int out_size, void* d_ws,
                              size_t ws_size, hipStream_t stream) {
  const float* gt = (const float*)d_in[0];       // (128,64,4)
  const float* anchors = (const float*)d_in[1];  // (3125,4)
  float* out = (float*)d_out;
  int* pos_ws = (int*)d_ws;
  float* gtmax = (float*)d_ws + 64;  // 128*64 floats = 32 KB

  // No memset needed: k1 writes every gtmax slot (single writer per (b,g));
  // k3 writes pos_ws[0] unconditionally.
  k1_gtmax<<<2048, 256, 0, stream>>>(gt, anchors, gtmax);
  k2_anchor<<<dim3(13, B_), 256, 0, stream>>>(gt, anchors, gtmax, out);
  k3_caps<<<B_, 256, 0, stream>>>(out, pos_ws);

  const int nbw = B_ * A_ * S_ * S_;  // 400000
  at_bw_kernel<<<(nbw + 255) / 256, 256, 0, stream>>>(out + CLS_OFF,
                                                      out + BW_OFF, pos_ws);
}